// Round 6
// baseline (2790.640 us; speedup 1.0000x reference)
//
#include <hip/hip_runtime.h>
#include <hip/hip_fp16.h>
#include <math.h>

// Problem constants
#define BB 256
#define NN 32
#define HH 256
#define FF 7
#define TT 496

typedef _Float16 f16x2 __attribute__((ext_vector_type(2)));
typedef _Float16 f16x4 __attribute__((ext_vector_type(4)));
typedef _Float16 f16x8 __attribute__((ext_vector_type(8)));

#if defined(__has_builtin)
#  if __has_builtin(__builtin_amdgcn_fdot2)
#    define HAS_FDOT2 1
#  endif
#endif

__device__ __forceinline__ float dot2f(f16x2 a, f16x2 b, float c) {
#ifdef HAS_FDOT2
  return __builtin_amdgcn_fdot2(a, b, c, false);
#else
  return fmaf((float)a[1], (float)b[1], fmaf((float)a[0], (float)b[0], c));
#endif
}

// fast sigmoid/tanh via v_exp_f32 + v_rcp_f32 (err ~1e-6, far under tolerance)
__device__ __forceinline__ float fsigm(float x) {
  float e = __builtin_amdgcn_exp2f(x * -1.44269504f);
  return __builtin_amdgcn_rcpf(1.f + e);
}
__device__ __forceinline__ float ftanh(float x) {
  float e = __builtin_amdgcn_exp2f(x * 2.88539008f);
  return 1.f - 2.f * __builtin_amdgcn_rcpf(e + 1.f);
}

#define SH2(V, L) __builtin_shufflevector(V, V, 2 * (L), 2 * (L) + 1)
#define SH01(V) __builtin_shufflevector(V, V, 0, 1)
#define SH23(V) __builtin_shufflevector(V, V, 2, 3)

// ---- workspace layout ----
// Node GRU combined weights W_eff[k][o], o in [0,1024):
//   o<256: r (Wih_h+Whh), [256,512): z (Wih_h+Whh), [512,768): i_n (Wih_h),
//   [768,1024): h_n (Whh rows 512..768)
// Per-thread (kp = t>>8 covers k in [kp*64, +64), oc = t&255 covers outputs oc+256q):
//   k-local [0,40): registers (20 f16x8), [40,48): LDS (4), [48,64): streamed (8).
// Half-index offsets:
#define H_WREG 0         // [kp][20][256] f16x8 = 163840 halves
#define H_WLDS 163840    // [kp][4][256]  f16x8 = 32768
#define H_WSTR 196608    // [kp][8][256]  f16x8 = 65536
#define H_WTG  262144    // [128 kpair][768 oc2] f16x4 {k0o0,k1o0,k0o1,k1o1} = 393216
#define H_AB   655360    // A2[7][768] then B2[7][768] = 10752
#define H_GB   666112    // bih_graph[768], bhh_graph[768] = 1536
#define H_WS1A 667648    // [(kq*64+u2)*8+kk] = Ws1[u2][kq*16+kk], kk<8   = 8192
#define H_WS1B 675840    // same, kk in [8,16)                            = 8192
// Float-index offsets:
#define F_HB    342016   // 256 f32: bhh_node[512+u]
#define F_PROBS 342272   // 256*496 f32

// prep element-index segments
#define S_WREG_END 163840
#define S_WLDS_END 196608
#define S_WSTR_END 262144
#define S_WTG_END  655360
#define S_AB_END   666112
#define S_GB_END   667648
#define S_WS1A_END 675840
#define S_WS1B_END 684032
#define PREP_N     684288   // +256 HB floats

__device__ __forceinline__ float weff(const float* Wih, const float* Whh, int k, int o) {
  if (o < 512) return Wih[o * 270 + 14 + k] + Whh[o * 256 + k];
  if (o < 768) return Wih[o * 270 + 14 + k];
  return Whh[(o - 256) * 256 + k];
}

__global__ void prep_kernel(const float* __restrict__ Wih_node,
                            const float* __restrict__ Whh_node,
                            const float* __restrict__ bih_node,
                            const float* __restrict__ bhh_node,
                            const float* __restrict__ Wih_graph,
                            const float* __restrict__ Whh_graph,
                            const float* __restrict__ bih_graph,
                            const float* __restrict__ bhh_graph,
                            const float* __restrict__ Ws1,
                            float* __restrict__ ws) {
  int idx = blockIdx.x * blockDim.x + threadIdx.x;
  if (idx >= PREP_N) return;
  __half* hw = (__half*)ws;
  if (idx < S_WREG_END) {
    int e = idx & 7, s = idx >> 3;
    int oc = s & 255, r = s >> 8;        // r in [0,80)
    int pr = r % 20, kp = r / 20;
    int q = e >> 1, kb = e & 1;
    int k = kp * 64 + pr * 2 + kb;
    int o = oc + (q << 8);
    hw[H_WREG + idx] = __float2half(weff(Wih_node, Whh_node, k, o));
  } else if (idx < S_WLDS_END) {
    int i = idx - S_WREG_END;
    int e = i & 7, s = i >> 3;
    int oc = s & 255, r = s >> 8;        // r in [0,16)
    int pr = r % 4, kp = r / 4;
    int q = e >> 1, kb = e & 1;
    int k = kp * 64 + 40 + pr * 2 + kb;
    int o = oc + (q << 8);
    hw[H_WLDS + i] = __float2half(weff(Wih_node, Whh_node, k, o));
  } else if (idx < S_WSTR_END) {
    int i = idx - S_WLDS_END;
    int e = i & 7, s = i >> 3;
    int oc = s & 255, r = s >> 8;        // r in [0,32)
    int pr = r % 8, kp = r / 8;
    int q = e >> 1, kb = e & 1;
    int k = kp * 64 + 48 + pr * 2 + kb;
    int o = oc + (q << 8);
    hw[H_WSTR + i] = __float2half(weff(Wih_node, Whh_node, k, o));
  } else if (idx < S_WTG_END) {
    int i = idx - S_WSTR_END;
    int e = i & 3, s = i >> 2;
    int kb = e & 1, ob = e >> 1;
    int oc2 = s % 768, kpair = s / 768;
    int k = 2 * kpair + kb, o = 2 * oc2 + ob;
    float v = (o < 768) ? Wih_graph[o * 256 + k] : Whh_graph[(o - 768) * 256 + k];
    hw[H_WTG + i] = __float2half(v);
  } else if (idx < S_AB_END) {
    int i = idx - S_WTG_END;
    float v;
    if (i < 5376) {
      int ci = i / 768, o = i % 768;
      v = Wih_node[o * 270 + ci] + bih_node[o] + ((o < 512) ? bhh_node[o] : 0.f);
    } else {
      int i2 = i - 5376;
      int cj = i2 / 768, o = i2 % 768;
      v = Wih_node[o * 270 + 7 + cj];
    }
    hw[H_AB + i] = __float2half(v);
  } else if (idx < S_GB_END) {
    int i = idx - S_AB_END;
    float v = (i < 768) ? bih_graph[i] : bhh_graph[i - 768];
    hw[H_GB + i] = __float2half(v);
  } else if (idx < S_WS1A_END) {
    int i = idx - S_GB_END;
    int kk = i & 7, r = i >> 3;
    int u2 = r & 63, kq = r >> 6;
    hw[H_WS1A + i] = __float2half(Ws1[u2 * 256 + kq * 16 + kk]);
  } else if (idx < S_WS1B_END) {
    int i = idx - S_WS1A_END;
    int kk = i & 7, r = i >> 3;
    int u2 = r & 63, kq = r >> 6;
    hw[H_WS1B + i] = __float2half(Ws1[u2 * 256 + kq * 16 + 8 + kk]);
  } else {
    int u = idx - S_WS1B_END;
    ws[F_HB + u] = bhh_node[512 + u];
  }
}

#define PAIR(Wv, Hv, L) { \
  f16x2 h2_ = SH2(Hv, L); \
  s0 = dot2f(h2_, SH2(Wv, 0), s0); \
  s1 = dot2f(h2_, SH2(Wv, 1), s1); \
  s2 = dot2f(h2_, SH2(Wv, 2), s2); \
  s3 = dot2f(h2_, SH2(Wv, 3), s3); }

#define MLPPART() { \
  const int u2_ = t & 63, kq_ = t >> 6; \
  f16x8 wa_ = ((const f16x8*)s_ws1a)[(kq_ << 6) + u2_]; \
  f16x8 wb_ = ((const f16x8*)s_ws1b)[(kq_ << 6) + u2_]; \
  const f16x8* nhp_ = (const f16x8*)nh2 + (kq_ << 1); \
  f16x8 ha_ = nhp_[0], hb_ = nhp_[1]; \
  float p_ = 0.f; \
  p_ = dot2f(SH2(ha_, 0), SH2(wa_, 0), p_); \
  p_ = dot2f(SH2(ha_, 1), SH2(wa_, 1), p_); \
  p_ = dot2f(SH2(ha_, 2), SH2(wa_, 2), p_); \
  p_ = dot2f(SH2(ha_, 3), SH2(wa_, 3), p_); \
  p_ = dot2f(SH2(hb_, 0), SH2(wb_, 0), p_); \
  p_ = dot2f(SH2(hb_, 1), SH2(wb_, 1), p_); \
  p_ = dot2f(SH2(hb_, 2), SH2(wb_, 2), p_); \
  p_ = dot2f(SH2(hb_, 3), SH2(wb_, 3), p_); \
  part2[kq_][u2_] = p_; }

#define MLPRED(dst) { \
  int v_ = t - 960; \
  float hv_ = part2[0][v_]+part2[1][v_]+part2[2][v_]+part2[3][v_] \
            + part2[4][v_]+part2[5][v_]+part2[6][v_]+part2[7][v_] \
            + part2[8][v_]+part2[9][v_]+part2[10][v_]+part2[11][v_] \
            + part2[12][v_]+part2[13][v_]+part2[14][v_]+part2[15][v_] + s_bs1[v_]; \
  hv_ = fmaxf(hv_, 0.f); \
  float c2_ = hv_ * s_ws2[v_]; \
  for (int off_ = 32; off_ > 0; off_ >>= 1) c2_ += __shfl_down(c2_, off_); \
  if (v_ == 0) dst = fsigm(c2_ + s_bs2); }

__global__ __launch_bounds__(1024) void rnn_kernel(
    const float* __restrict__ z,
    const float* __restrict__ nf,
    const float* __restrict__ bs1,
    const float* __restrict__ Ws2,
    const float* __restrict__ bs2,
    float* __restrict__ ws) {
  __shared__ __align__(16) __half s_wl[32768];   // 64 KB LDS weight zone
  __shared__ __align__(16) __half s_a2[5376];
  __shared__ __align__(16) __half s_b2[5376];
  __shared__ __align__(16) __half s_ws1a[8192];
  __shared__ __align__(16) __half s_ws1b[8192];
  __shared__ __align__(16) __half s_gbi[768];
  __shared__ __align__(16) __half s_gbh[768];
  __shared__ __align__(16) float s_hb[256];
  __shared__ __align__(16) float nh[256];
  __shared__ __align__(16) __half nh2[256];
  __shared__ __align__(16) float gh2[256];
  __shared__ __align__(16) __half gh2h[256];
  __shared__ __align__(16) float part[4][1024];
  __shared__ __align__(16) float part2[16][64];
  __shared__ float s_bs1[64], s_ws2[64];
  __shared__ int cls[NN];
  __shared__ float s_bs2;

  const int b = blockIdx.x, t = threadIdx.x;
  const __half* hws = (const __half*)ws;
  float* probs = ws + F_PROBS + (size_t)b * TT;

  // ---- stage LDS ----
  {
    f16x8* dst = (f16x8*)s_wl;
    const f16x8* src = (const f16x8*)(hws + H_WLDS);
    for (int x = t; x < 4096; x += 1024) dst[x] = src[x];
  }
  for (int x = t; x < 5376; x += 1024) {
    s_a2[x] = hws[H_AB + x];
    s_b2[x] = hws[H_AB + 5376 + x];
  }
  for (int x = t; x < 8192; x += 1024) {
    s_ws1a[x] = hws[H_WS1A + x];
    s_ws1b[x] = hws[H_WS1B + x];
  }
  if (t < 768) {
    s_gbi[t] = hws[H_GB + t];
    s_gbh[t] = hws[H_GB + 768 + t];
  }
  if (t < 256) {
    s_hb[t] = ws[F_HB + t];
    float v = z[b * 256 + t];
    nh[t] = v; gh2[t] = v;
    __half vh = __float2half(v);
    nh2[t] = vh; gh2h[t] = vh;
  }
  if (t < 64) { s_bs1[t] = bs1[t]; s_ws2[t] = Ws2[t]; }
  if (t == 0) s_bs2 = bs2[0];
  if (t < NN) {
    const float* row = nf + (b * NN + t) * FF;
    int c = 0;
#pragma unroll
    for (int q = 1; q < FF; ++q)
      if (row[q] > 0.5f) c = q;
    cls[t] = c;
  }

  const int kp = t >> 8;      // k-partition (wave-uniform)
  const int oc = t & 255;     // output column; outputs oc+256q

  // ---- node weights: 20 resident f16x8 (80 VGPR), keep-alive enforced ----
  const f16x8* wreg = (const f16x8*)(hws + H_WREG) + (kp * 20) * 256 + oc;
  f16x8 W0 = wreg[0 * 256],  W1 = wreg[1 * 256],  W2 = wreg[2 * 256],  W3 = wreg[3 * 256];
  f16x8 W4 = wreg[4 * 256],  W5 = wreg[5 * 256],  W6 = wreg[6 * 256],  W7 = wreg[7 * 256];
  f16x8 W8 = wreg[8 * 256],  W9 = wreg[9 * 256],  W10 = wreg[10 * 256], W11 = wreg[11 * 256];
  f16x8 W12 = wreg[12 * 256], W13 = wreg[13 * 256], W14 = wreg[14 * 256], W15 = wreg[15 * 256];
  f16x8 W16 = wreg[16 * 256], W17 = wreg[17 * 256], W18 = wreg[18 * 256], W19 = wreg[19 * 256];

  const f16x8* stp = (const f16x8*)(hws + H_WSTR) + (kp * 8) * 256 + oc;
  const f16x8* swl = (const f16x8*)s_wl + (kp * 4) * 256 + oc;
  const f16x8* hv8 = (const f16x8*)nh2 + (kp << 3);
  __syncthreads();

  int base = 0;
  for (int i = 0; i < NN - 1; ++i) {
    const __half* ArH = s_a2 + cls[i] * 768;

    for (int j = i + 1; j < NN; ++j) {
      const __half* BrH = s_b2 + cls[j] * 768;
      const bool pend = (j > i + 1);
      // pin W0..W19 in VGPRs across the loop (defeat rematerialization)
      asm volatile("" : "+v"(W0), "+v"(W1), "+v"(W2), "+v"(W3), "+v"(W4),
                        "+v"(W5), "+v"(W6), "+v"(W7), "+v"(W8), "+v"(W9),
                        "+v"(W10), "+v"(W11), "+v"(W12), "+v"(W13), "+v"(W14),
                        "+v"(W15), "+v"(W16), "+v"(W17), "+v"(W18), "+v"(W19));
      // ====== Phase A ======
      float s0 = 0.f, s1 = 0.f, s2 = 0.f, s3 = 0.f;
      // stream group 1 (issue early, consume at H6)
      f16x8 S0 = stp[0 * 256], S1 = stp[1 * 256], S2 = stp[2 * 256], S3 = stp[3 * 256];
      {
        f16x8 H0 = hv8[0], H1 = hv8[1];
        PAIR(W0, H0, 0) PAIR(W1, H0, 1) PAIR(W2, H0, 2) PAIR(W3, H0, 3)
        PAIR(W4, H1, 0) PAIR(W5, H1, 1) PAIR(W6, H1, 2) PAIR(W7, H1, 3)
      }
      // stream group 2 (consume at H7)
      f16x8 S4 = stp[4 * 256], S5 = stp[5 * 256], S6 = stp[6 * 256], S7 = stp[7 * 256];
      {
        f16x8 H2 = hv8[2], H3 = hv8[3], H4 = hv8[4];
        PAIR(W8, H2, 0)  PAIR(W9, H2, 1)  PAIR(W10, H2, 2) PAIR(W11, H2, 3)
        PAIR(W12, H3, 0) PAIR(W13, H3, 1) PAIR(W14, H3, 2) PAIR(W15, H3, 3)
        PAIR(W16, H4, 0) PAIR(W17, H4, 1) PAIR(W18, H4, 2) PAIR(W19, H4, 3)
      }
      {
        f16x8 H5 = hv8[5];
        f16x8 L0 = swl[0 * 256], L1 = swl[1 * 256], L2 = swl[2 * 256], L3 = swl[3 * 256];
        PAIR(L0, H5, 0) PAIR(L1, H5, 1) PAIR(L2, H5, 2) PAIR(L3, H5, 3)
      }
      {
        f16x8 H6 = hv8[6], H7 = hv8[7];
        PAIR(S0, H6, 0) PAIR(S1, H6, 1) PAIR(S2, H6, 2) PAIR(S3, H6, 3)
        PAIR(S4, H7, 0) PAIR(S5, H7, 1) PAIR(S6, H7, 2) PAIR(S7, H7, 3)
      }
      part[kp][oc] = s0;
      part[kp][oc + 256] = s1;
      part[kp][oc + 512] = s2;
      part[kp][oc + 768] = s3;
      if (pend) MLPPART()
      __syncthreads();
      // ====== Phase B ======
      if (t < 256) {
        const int u = t;
        float pr  = part[0][u]       + part[1][u]       + part[2][u]       + part[3][u];
        float pz  = part[0][256 + u] + part[1][256 + u] + part[2][256 + u] + part[3][256 + u];
        float pin = part[0][512 + u] + part[1][512 + u] + part[2][512 + u] + part[3][512 + u];
        float phn = part[0][768 + u] + part[1][768 + u] + part[2][768 + u] + part[3][768 + u];
        float ar = (float)ArH[u]       + (float)BrH[u];
        float az = (float)ArH[256 + u] + (float)BrH[256 + u];
        float an = (float)ArH[512 + u] + (float)BrH[512 + u];
        float r  = fsigm(pr + ar);
        float zg = fsigm(pz + az);
        float n2 = ftanh(pin + an + r * (phn + s_hb[u]));
        float nv = (1.f - zg) * n2 + zg * nh[u];
        nh[u] = nv;
        nh2[u] = __float2half(nv);
      } else if (pend && t >= 960) {
        MLPRED(probs[base + j - i - 2])
      }
      __syncthreads();
    }

    // ====== Graph GRU step (f16 weights streamed, dot2) ======
    {
      if (t < 768) {
        const __half* hsrc2 = (t < 384) ? nh2 : gh2h;   // wave-uniform
        const f16x8* hg = (const f16x8*)hsrc2;
        const f16x4* wg = (const f16x4*)(hws + H_WTG) + t;
        float g0 = 0.f, g1 = 0.f;
#pragma unroll 8
        for (int c = 0; c < 32; ++c) {
          f16x8 Hc = hg[c];
          f16x4 a0 = wg[(c * 4 + 0) * 768];
          f16x4 a1 = wg[(c * 4 + 1) * 768];
          f16x4 a2 = wg[(c * 4 + 2) * 768];
          f16x4 a3 = wg[(c * 4 + 3) * 768];
          g0 = dot2f(SH2(Hc, 0), SH01(a0), g0); g1 = dot2f(SH2(Hc, 0), SH23(a0), g1);
          g0 = dot2f(SH2(Hc, 1), SH01(a1), g0); g1 = dot2f(SH2(Hc, 1), SH23(a1), g1);
          g0 = dot2f(SH2(Hc, 2), SH01(a2), g0); g1 = dot2f(SH2(Hc, 2), SH23(a2), g1);
          g0 = dot2f(SH2(Hc, 3), SH01(a3), g0); g1 = dot2f(SH2(Hc, 3), SH23(a3), g1);
        }
        ((float*)part)[(t << 1)] = g0;
        ((float*)part)[(t << 1) + 1] = g1;
      }
      MLPPART()                   // MLP hidden-part for prob (i, NN-1)
      __syncthreads();
      if (t < 256) {
        const int u = t;
        const float* pf = (const float*)part;
        float gir = pf[u]        + (float)s_gbi[u];
        float giz = pf[256 + u]  + (float)s_gbi[256 + u];
        float gin = pf[512 + u]  + (float)s_gbi[512 + u];
        float ghr = pf[768 + u]  + (float)s_gbh[u];
        float ghz = pf[1024 + u] + (float)s_gbh[256 + u];
        float ghn = pf[1280 + u] + (float)s_gbh[512 + u];
        float r  = fsigm(gir + ghr);
        float zg = fsigm(giz + ghz);
        float n2 = ftanh(gin + r * ghn);
        float nv = (1.f - zg) * n2 + zg * gh2[u];
        gh2[u] = nv; nh[u] = nv;
        __half vh = __float2half(nv);
        gh2h[u] = vh; nh2[u] = vh;
      } else if (t >= 960) {
        MLPRED(probs[base + NN - 2 - i])
      }
      __syncthreads();
    }
    base += NN - 1 - i;
  }
}

// ContinuousBernoulli icdf + anti-diagonal scatter into adj
__global__ void edges_kernel(const float* __restrict__ u,
                             const float* __restrict__ ws,
                             float* __restrict__ adj) {
  int idx = blockIdx.x * blockDim.x + threadIdx.x;
  if (idx >= BB * TT) return;
  int b = idx / TT, t = idx % TT;
  float prob = ws[F_PROBS + (size_t)b * TT + t];
  float uu = u[idx];
  const float EPSF = 1.1920929e-07f;
  float p = fminf(fmaxf(prob, EPSF), 1.0f - EPSF);
  bool outside = (p < 0.499f) || (p > 0.501f);
  float cut = outside ? p : 0.499f;
  float stable = (log1pf(fmaf(uu, 2.f * cut - 1.f, -cut)) - log1pf(-cut)) /
                 (logf(cut) - log1pf(-cut));
  float e = outside ? stable : uu;
  int d = (int)((1.0f + sqrtf(1.0f + 8.0f * (float)t)) * 0.5f);
  while (d * (d + 1) / 2 <= t) ++d;
  while (d * (d - 1) / 2 > t) --d;
  int k = t - d * (d - 1) / 2;
  int r = k, c = k + (NN - d);
  adj[((size_t)b * NN + r) * NN + c] = e;
  adj[((size_t)b * NN + c) * NN + r] = e;
}

__global__ void xb_kernel(const float* __restrict__ nf,
                          float* __restrict__ out_x,
                          float* __restrict__ out_batch) {
  int idx = blockIdx.x * blockDim.x + threadIdx.x;
  if (idx < BB * NN * FF) out_x[idx] = nf[idx];
  if (idx < BB * NN) out_batch[idx] = (float)(idx >> 5);
}

extern "C" void kernel_launch(void* const* d_in, const int* in_sizes, int n_in,
                              void* d_out, int out_size, void* d_ws, size_t ws_size,
                              hipStream_t stream) {
  const float* z         = (const float*)d_in[0];
  const float* nf        = (const float*)d_in[1];
  const float* u         = (const float*)d_in[2];
  const float* Wih_node  = (const float*)d_in[3];
  const float* Whh_node  = (const float*)d_in[4];
  const float* bih_node  = (const float*)d_in[5];
  const float* bhh_node  = (const float*)d_in[6];
  const float* Wih_graph = (const float*)d_in[7];
  const float* Whh_graph = (const float*)d_in[8];
  const float* bih_graph = (const float*)d_in[9];
  const float* bhh_graph = (const float*)d_in[10];
  const float* Ws1       = (const float*)d_in[11];
  const float* bs1       = (const float*)d_in[12];
  const float* Ws2       = (const float*)d_in[13];
  const float* bs2       = (const float*)d_in[14];

  float* ws = (float*)d_ws;
  float* out_x   = (float*)d_out;                        // [B*N, F]
  float* out_adj = out_x + BB * NN * FF;                 // [B, N, N]
  float* out_batch = out_x + BB * NN * FF + (size_t)BB * NN * NN;

  hipMemsetAsync(out_adj, 0, (size_t)BB * NN * NN * sizeof(float), stream);
  prep_kernel<<<(PREP_N + 255) / 256, 256, 0, stream>>>(
      Wih_node, Whh_node, bih_node, bhh_node,
      Wih_graph, Whh_graph, bih_graph, bhh_graph, Ws1, ws);
  rnn_kernel<<<BB, 1024, 0, stream>>>(z, nf, bs1, Ws2, bs2, ws);
  xb_kernel<<<(BB * NN * FF + 255) / 256, 256, 0, stream>>>(nf, out_x, out_batch);
  edges_kernel<<<(BB * TT + 255) / 256, 256, 0, stream>>>(u, ws, out_adj);
}